// Round 8
// baseline (239.317 us; speedup 1.0000x reference)
//
#include <hip/hip_runtime.h>

// MHA forward. Inputs/output f32; internal bf16 MFMA pipeline.
// b=2, s=2048, d_model=1024, heads=16, head_dim=64.
// cvt (f32->bf16) -> fused QKV gemm128 (Q,K permuted via LDS repack, Q
// pre-scaled by 1/sqrt(hd)*log2e; V written TRANSPOSED [bh][d][s]) ->
// attn6 (branch-free units, V LDS dbuf, register-resident P, no scale mults)
// -> gemm64 (O x Wo^T -> f32).

typedef __bf16 bf16_t;
typedef __attribute__((ext_vector_type(8))) __bf16 bf16x8;
typedef __attribute__((ext_vector_type(4))) __bf16 bf16x4;
typedef __attribute__((ext_vector_type(4))) short s16x4;
typedef __attribute__((ext_vector_type(4))) float f32x4;

#define MFMA16 __builtin_amdgcn_mfma_f32_16x16x32_bf16
#define MFMA16K16 __builtin_amdgcn_mfma_f32_16x16x16bf16_1k

__device__ __forceinline__ bf16_t f2bf(float x) {
  unsigned u = __float_as_uint(x);
  unsigned r = (u + 0x7fffu + ((u >> 16) & 1u)) >> 16;
  unsigned short s = (unsigned short)r;
  return __builtin_bit_cast(bf16_t, s);
}

// pack two f32 -> u32 of two bf16 (round-half-up): lo16 = bf16(a), hi16 = bf16(b)
__device__ __forceinline__ unsigned pkbf(float a, float b) {
  unsigned ua = __float_as_uint(a) + 0x8000u;
  unsigned ub = __float_as_uint(b) + 0x8000u;
  return __builtin_amdgcn_perm(ub, ua, 0x07060302u);
}

// async global->LDS, 16B per lane. LDS dest must be wave-uniform base + lane*16.
__device__ __forceinline__ void gld_lds16(const bf16_t* g, bf16_t* l) {
  __builtin_amdgcn_global_load_lds(
      (const __attribute__((address_space(1))) unsigned int*)g,
      (__attribute__((address_space(3))) unsigned int*)l, 16, 0, 0);
}

// ---------------- convert: x -> Xb, {Wq,Wk,Wv} -> Wqkv concat, Wo -> Wob ----
__global__ __launch_bounds__(256) void cvt_kernel(const float4* __restrict__ x,
                                                  const float4* __restrict__ wq,
                                                  const float4* __restrict__ wk,
                                                  const float4* __restrict__ wv,
                                                  const float4* __restrict__ wo,
                                                  bf16x4* __restrict__ xb,
                                                  bf16x4* __restrict__ wqkv,
                                                  bf16x4* __restrict__ wob) {
  const int NX = (2 * 2048 * 1024) / 4;  // 2,097,152
  const int NW = (1024 * 1024) / 4;      // 262,144 = 2^18
  const int TOT = NX + 4 * NW;
  for (int i = blockIdx.x * 256 + threadIdx.x; i < TOT; i += gridDim.x * 256) {
    const float4* s;
    bf16x4* d;
    if (i < NX) {
      s = x + i; d = xb + i;
    } else {
      int t = i - NX;
      int w = t >> 18;
      int o = t & (NW - 1);
      if (w == 0)      { s = wq + o; d = wqkv + o; }
      else if (w == 1) { s = wk + o; d = wqkv + NW + o; }
      else if (w == 2) { s = wv + o; d = wqkv + 2 * NW + o; }
      else             { s = wo + o; d = wob + o; }
    }
    float4 v = *s;
    bf16x4 h;
    h[0] = f2bf(v.x); h[1] = f2bf(v.y); h[2] = f2bf(v.z); h[3] = f2bf(v.w);
    *d = h;
  }
}

// ---------------- QKV GEMM: C[M,N] = A[M,K] * B[N,K]^T -----------------------
// Q,K blocks: LDS repack -> vectorized 16B stores to [b,h,s,hd] (Q pre-scaled).
// V blocks: LDS-transpose epilogue -> Vt[bh][d][s]. 128x128x64, grid (24,32).
__global__ __launch_bounds__(256) void gemm128(const bf16_t* __restrict__ A,
                                               const bf16_t* __restrict__ B,
                                               bf16_t* __restrict__ Qo,
                                               bf16_t* __restrict__ Ko,
                                               bf16_t* __restrict__ Vt,
                                               int M, int N, int K) {
  constexpr int TS = 137;  // V-transpose stride (odd: conflict-free col reads)
  constexpr int LR = 136;  // Q/K repack stride (mult of 8: 16B-aligned b128 rows)
  __shared__ __align__(16) bf16_t Sm[128 * TS];  // 35072B; aliases As/Bs staging
  bf16_t* As = Sm;
  bf16_t* Bs = Sm + 128 * 64;
  const int m0 = blockIdx.y * 128, n0 = blockIdx.x * 128;
  const int tid = threadIdx.x, lane = tid & 63;
  const int l15 = lane & 15, quad = lane >> 4;
  const int w = tid >> 6;
  const int wr = (w >> 1) * 64, wc = (w & 1) * 64;

  f32x4 acc[4][4];
#pragma unroll
  for (int i = 0; i < 4; i++)
#pragma unroll
    for (int j = 0; j < 4; j++) acc[i][j] = f32x4{0.f, 0.f, 0.f, 0.f};

  for (int k0 = 0; k0 < K; k0 += 64) {
    __syncthreads();
#pragma unroll
    for (int r = 0; r < 4; r++) {
      int c = r * 256 + tid;
      gld_lds16(A + (long)(m0 + (c >> 3)) * K + k0 + (c & 7) * 8, As + c * 8);
    }
#pragma unroll
    for (int r = 0; r < 4; r++) {
      int c = r * 256 + tid;
      gld_lds16(B + (long)(n0 + (c >> 3)) * K + k0 + (c & 7) * 8, Bs + c * 8);
    }
    __syncthreads();
#pragma unroll
    for (int ks = 0; ks < 2; ks++) {
      bf16x8 af[4], bv[4];
#pragma unroll
      for (int i = 0; i < 4; i++)
        af[i] = *(const bf16x8*)(As + (wr + i * 16 + l15) * 64 + ks * 32 + quad * 8);
#pragma unroll
      for (int j = 0; j < 4; j++)
        bv[j] = *(const bf16x8*)(Bs + (wc + j * 16 + l15) * 64 + ks * 32 + quad * 8);
#pragma unroll
      for (int i = 0; i < 4; i++)
#pragma unroll
        for (int j = 0; j < 4; j++) acc[i][j] = MFMA16(af[i], bv[j], acc[i][j], 0, 0, 0);
    }
  }

  const int mat = n0 >> 10;  // block entirely within one of Q/K/V (128 | 1024)
  const int hbase = (n0 & 1023) >> 6;  // first head in this 128-col span
  const int b = m0 >> 11;              // tile never crosses batch boundary
  const int sg0 = m0 & 2047;
  __syncthreads();  // all MFMA LDS reads done before Sm reuse

  if (mat < 2) {
    // scale2 = (1/sqrt(64))*log2(e), folded into Q before its single rounding
    const float sc = (mat == 0) ? 0.18033688011112042f : 1.0f;
    bf16_t* dst = (mat == 0) ? Qo : Ko;
#pragma unroll
    for (int i = 0; i < 4; i++)
#pragma unroll
      for (int j = 0; j < 4; j++) {
        int col = wc + j * 16 + l15;
#pragma unroll
        for (int r = 0; r < 4; r++) {
          int row = wr + i * 16 + quad * 4 + r;
          Sm[row * LR + col] = f2bf(acc[i][j][r] * sc);
        }
      }
    __syncthreads();
#pragma unroll
    for (int u = 0; u < 8; u++) {
      int id = u * 256 + tid;
      int row = id >> 4, ck = id & 15;  // 16 thr per row: b128 row reads, 2-way
      int head = hbase + (ck >> 3), hd0 = (ck & 7) * 8;
      bf16x8 v = *(const bf16x8*)(Sm + row * LR + ck * 8);
      *(bf16x8*)(dst + (((long)(b * 16 + head) * 2048 + (sg0 + row)) << 6) + hd0) = v;
    }
  } else {
    // V block: transpose 128(s) x 128(c) tile through LDS, write Vt[bh][d][s]
#pragma unroll
    for (int i = 0; i < 4; i++)
#pragma unroll
      for (int j = 0; j < 4; j++) {
        int col = wc + j * 16 + l15;
#pragma unroll
        for (int r = 0; r < 4; r++) {
          int row = wr + i * 16 + quad * 4 + r;
          Sm[row * TS + col] = f2bf(acc[i][j][r]);
        }
      }
    __syncthreads();
#pragma unroll
    for (int u = 0; u < 8; u++) {
      int id = u * 256 + tid;
      int col = id >> 4, sc = id & 15;  // consecutive tid -> consecutive s-chunk
      int head = hbase + (col >> 6), hd = col & 63;
      bf16x8 v;
#pragma unroll
      for (int vv = 0; vv < 8; vv++) v[vv] = Sm[(sc * 8 + vv) * TS + col];
      *(bf16x8*)(Vt + ((long)(b * 16 + head) * 64 + hd) * 2048 + sg0 + sc * 8) = v;
    }
  }
}

// ---------------- attention unit: one 64q x (JTN*16)kv step -----------------
// Branch-free; Q pre-scaled so no per-element scale. Mask only jt >= JM0
// (compile-time). S^T = K.Q^T; P^T packed in-register as B-frags of
// mfma_16x16x16bf16; O^T += V^T.P^T from LDS Vl.
template <int JTN, int JM0, int PS>
__device__ __forceinline__ void attn_unit(const bf16_t* __restrict__ Kb, int kv0,
                                          const bf16_t* Vlb, const bf16x8* qf,
                                          int q_abs, float& m_i, float& l_i,
                                          f32x4* Oacc, int l15, int quad) {
  f32x4 S[JTN];
#pragma unroll
  for (int jt = 0; jt < JTN; jt++) {
    const bf16_t* kr = Kb + (long)(kv0 + jt * 16 + l15) * 64 + quad * 8;
    bf16x8 ka = *(const bf16x8*)kr;
    bf16x8 kb = *(const bf16x8*)(kr + 32);
    f32x4 s = f32x4{0.f, 0.f, 0.f, 0.f};
    s = MFMA16(ka, qf[0], s, 0, 0, 0);
    s = MFMA16(kb, qf[1], s, 0, 0, 0);
    S[jt] = s;
  }
#pragma unroll
  for (int jt = JM0; jt < JTN; jt++) {
    int kvb = kv0 + jt * 16 + quad * 4;
#pragma unroll
    for (int r = 0; r < 4; r++)
      if (kvb + r > q_abs) S[jt][r] = -1e30f;
  }
  float mx = -1e30f;
#pragma unroll
  for (int jt = 0; jt < JTN; jt++)
#pragma unroll
    for (int r = 0; r < 4; r++) mx = fmaxf(mx, S[jt][r]);
  mx = fmaxf(mx, __shfl_xor(mx, 16, 64));
  mx = fmaxf(mx, __shfl_xor(mx, 32, 64));
  float mnew = fmaxf(m_i, mx);
  float alpha = exp2f(m_i - mnew);
  float rs = 0.f;
#pragma unroll
  for (int jt = 0; jt < JTN; jt++)
#pragma unroll
    for (int r = 0; r < 4; r++) {
      float pv = exp2f(S[jt][r] - mnew);
      S[jt][r] = pv;
      rs += pv;
    }
  rs += __shfl_xor(rs, 16, 64);
  rs += __shfl_xor(rs, 32, 64);
  l_i = l_i * alpha + rs;
  m_i = mnew;
#pragma unroll
  for (int n = 0; n < 4; n++) Oacc[n] *= alpha;
#pragma unroll
  for (int jt = 0; jt < JTN; jt++) {
    int2 pk;
    pk.x = (int)pkbf(S[jt][0], S[jt][1]);
    pk.y = (int)pkbf(S[jt][2], S[jt][3]);
    s16x4 pb = __builtin_bit_cast(s16x4, pk);
#pragma unroll
    for (int n = 0; n < 4; n++) {
      s16x4 av = *(const s16x4*)(Vlb + (n * 16 + l15) * PS + jt * 16 + quad * 4);
      Oacc[n] = MFMA16K16(av, pb, Oacc[n], 0, 0, 0);
    }
  }
}

// ---------------- flash attention -------------------------------------------
// Q(pre-scaled),K: [32][2048][64]; Vt: [32][64][2048]; O: [4096][1024].
// grid (32, 32 bh); block 256 (4 waves, wave w owns q rows w*16..w*16+15).
// qt = (y>>3)&1 ? 31-x : x  -> same-CU blocks get {x,31-x,x,31-x} = 34 units.
// V LDS double-buffer + register prefetch: ONE barrier per kv-tile.
__global__ __launch_bounds__(256, 4) void attn6(const bf16_t* __restrict__ Q,
                                                const bf16_t* __restrict__ Kp,
                                                const bf16_t* __restrict__ Vt,
                                                bf16_t* __restrict__ O) {
  constexpr int PS = 136;
  __shared__ __align__(16) bf16_t Vl[2][64 * PS];  // 2 x 17.4KB
  const int bh = blockIdx.y;
  const int qt = ((blockIdx.y >> 3) & 1) ? (31 - blockIdx.x) : blockIdx.x;
  const int q0 = qt * 64;
  const int nkt = (qt >> 1) + 1;
  const int tid = threadIdx.x, lane = tid & 63;
  const int l15 = lane & 15, quad = lane >> 4;
  const int w = tid >> 6;
  const bf16_t* Qb = Q + (long)bh * 2048 * 64;
  const bf16_t* Kb = Kp + (long)bh * 2048 * 64;
  const bf16_t* Vg = Vt + (long)bh * 64 * 2048;
  const int bb = bh >> 4, hh = bh & 15;

  bf16x8 qf[2];
#pragma unroll
  for (int ks = 0; ks < 2; ks++)
    qf[ks] = *(const bf16x8*)(Qb + (long)(q0 + w * 16 + l15) * 64 + ks * 32 + quad * 8);

  f32x4 Oacc[4];
#pragma unroll
  for (int n = 0; n < 4; n++) Oacc[n] = f32x4{0.f, 0.f, 0.f, 0.f};
  float m_i = -1e30f, l_i = 0.f;
  const int q_abs = q0 + w * 16 + l15;

  // stage V tile 0 -> Vl[0]  (64x128 = 256 thr x 4 x 16B)
  bf16x8 vr[4];
#pragma unroll
  for (int r = 0; r < 4; r++) {
    int c = r * 256 + tid;
    vr[r] = *(const bf16x8*)(Vg + (long)(c >> 4) * 2048 + (c & 15) * 8);
  }
#pragma unroll
  for (int r = 0; r < 4; r++) {
    int c = r * 256 + tid;
    *(bf16x8*)(&Vl[0][(c >> 4) * PS + (c & 15) * 8]) = vr[r];
  }

  for (int kt = 0; kt < nkt - 1; kt++) {  // full (unmasked) tiles
    const bf16_t* Vcur = &Vl[kt & 1][0];
    bf16_t* Vnxt = &Vl[(kt + 1) & 1][0];
    __syncthreads();  // Vl[kt&1] staged; all waves past previous tile's reads
    const int kvn = (kt + 1) * 128;
#pragma unroll
    for (int r = 0; r < 4; r++) {  // prefetch next V tile
      int c = r * 256 + tid;
      vr[r] = *(const bf16x8*)(Vg + (long)(c >> 4) * 2048 + kvn + (c & 15) * 8);
    }
    attn_unit<8, 8, PS>(Kb, kt * 128, Vcur, qf, q_abs, m_i, l_i, Oacc, l15, quad);
#pragma unroll
    for (int r = 0; r < 4; r++) {
      int c = r * 256 + tid;
      *(bf16x8*)(&Vnxt[(c >> 4) * PS + (c & 15) * 8]) = vr[r];
    }
  }

  __syncthreads();
  const bf16_t* Vlast = &Vl[(nkt - 1) & 1][0];
  const int kvl = (nkt - 1) * 128;
  if (qt & 1)
    attn_unit<8, 4, PS>(Kb, kvl, Vlast, qf, q_abs, m_i, l_i, Oacc, l15, quad);
  else
    attn_unit<4, 0, PS>(Kb, kvl, Vlast, qf, q_abs, m_i, l_i, Oacc, l15, quad);

  // epilogue: lane holds O^T[d=n*16+quad*4+r][q=l15] -> O[row q][col hh*64+d]
  const float inv = 1.0f / l_i;
  bf16_t* orow = O + ((long)bb * 2048 + q_abs) * 1024 + hh * 64;
#pragma unroll
  for (int n = 0; n < 4; n++) {
    int2 pk;
    pk.x = (int)pkbf(Oacc[n][0] * inv, Oacc[n][1] * inv);
    pk.y = (int)pkbf(Oacc[n][2] * inv, Oacc[n][3] * inv);
    *(int2*)(orow + n * 16 + quad * 4) = pk;
  }
}

// ---------------- final GEMM: C[M,N] f32 = A[M,K] bf16 * B[N,K]^T bf16 ------
// 128x64x64 tile, 4 waves row-split (32 rows each). grid (N/64, M/128) = 512.
__global__ __launch_bounds__(256) void gemm64(const bf16_t* __restrict__ A,
                                              const bf16_t* __restrict__ B,
                                              float* __restrict__ C,
                                              int M, int N, int K) {
  __shared__ __align__(16) bf16_t As[128 * 64];
  __shared__ __align__(16) bf16_t Bs[64 * 64];
  const int m0 = blockIdx.y * 128, n0 = blockIdx.x * 64;
  const int tid = threadIdx.x, lane = tid & 63;
  const int l15 = lane & 15, quad = lane >> 4;
  const int w = tid >> 6;

  f32x4 acc[2][4];
#pragma unroll
  for (int i = 0; i < 2; i++)
#pragma unroll
    for (int j = 0; j < 4; j++) acc[i][j] = f32x4{0.f, 0.f, 0.f, 0.f};

  for (int k0 = 0; k0 < K; k0 += 64) {
    __syncthreads();
#pragma unroll
    for (int r = 0; r < 4; r++) {
      int c = r * 256 + tid;
      gld_lds16(A + (long)(m0 + (c >> 3)) * K + k0 + (c & 7) * 8, As + c * 8);
    }
#pragma unroll
    for (int r = 0; r < 2; r++) {
      int c = r * 256 + tid;
      gld_lds16(B + (long)(n0 + (c >> 3)) * K + k0 + (c & 7) * 8, Bs + c * 8);
    }
    __syncthreads();
#pragma unroll
    for (int ks = 0; ks < 2; ks++) {
      bf16x8 af[2], bv[4];
#pragma unroll
      for (int i = 0; i < 2; i++)
        af[i] = *(const bf16x8*)(As + (w * 32 + i * 16 + l15) * 64 + ks * 32 + quad * 8);
#pragma unroll
      for (int j = 0; j < 4; j++)
        bv[j] = *(const bf16x8*)(Bs + (j * 16 + l15) * 64 + ks * 32 + quad * 8);
#pragma unroll
      for (int i = 0; i < 2; i++)
#pragma unroll
        for (int j = 0; j < 4; j++) acc[i][j] = MFMA16(af[i], bv[j], acc[i][j], 0, 0, 0);
    }
  }

#pragma unroll
  for (int i = 0; i < 2; i++)
#pragma unroll
    for (int j = 0; j < 4; j++) {
      int col = n0 + j * 16 + l15;
#pragma unroll
      for (int r = 0; r < 4; r++) {
        int row = m0 + w * 32 + i * 16 + quad * 4 + r;
        C[(long)row * N + col] = acc[i][j][r];
      }
    }
}

// ============================================================================
extern "C" void kernel_launch(void* const* d_in, const int* in_sizes, int n_in,
                              void* d_out, int out_size, void* d_ws, size_t ws_size,
                              hipStream_t stream) {
  const float* x = (const float*)d_in[0];
  const float* Wq = (const float*)d_in[1];
  const float* Wk = (const float*)d_in[2];
  const float* Wv = (const float*)d_in[3];
  const float* Wo = (const float*)d_in[4];
  float* out = (float*)d_out;

  const long M4 = 4L * 1024 * 1024;  // 4M bf16 elems = 8MB
  dim3 blk(256);

  bf16_t* Qb = (bf16_t*)d_ws;      // [32][2048][64] (pre-scaled)
  bf16_t* Kb = Qb + M4;            // [32][2048][64]
  bf16_t* Ob = Kb + M4;            // [4096][1024] (attn output)
  bf16_t* Vtg = Ob + M4;           // [32][64][2048] (V transposed, from gemm128)
  bf16_t* Xb = Vtg + M4;           // [4096][1024]
  bf16_t* Wqkv = Xb + M4;          // [3072][1024]
  bf16_t* Wob = Wqkv + 3L * 1024 * 1024;  // [1024][1024]

  cvt_kernel<<<4096, blk, 0, stream>>>((const float4*)x, (const float4*)Wq,
                                       (const float4*)Wk, (const float4*)Wv,
                                       (const float4*)Wo, (bf16x4*)Xb,
                                       (bf16x4*)Wqkv, (bf16x4*)Wob);
  gemm128<<<dim3(24, 32), blk, 0, stream>>>(Xb, Wqkv, Qb, Kb, Vtg, 4096, 3072, 1024);
  attn6<<<dim3(32, 32), blk, 0, stream>>>(Qb, Kb, Vtg, Ob);
  gemm64<<<dim3(16, 32), blk, 0, stream>>>(Ob, Wob, out, 4096, 1024, 1024);
}

// Round 9
// 233.807 us; speedup vs baseline: 1.0236x; 1.0236x over previous
//
#include <hip/hip_runtime.h>

// MHA forward. Inputs/output f32; internal bf16 MFMA pipeline.
// b=2, s=2048, d_model=1024, heads=16, head_dim=64.
// cvt (f32->bf16) -> fused QKV gemm128 (Q,K permuted via LDS repack, Q
// pre-scaled by 1/sqrt(hd)*log2e; V written TRANSPOSED [bh][d][s]) ->
// attn7 (XCD-localized grid: each head pinned to one XCD so K/V live in its
// L2; balanced 34 units/CU; V LDS dbuf, register-resident P) ->
// gemm64 (O x Wo^T -> f32).

typedef __bf16 bf16_t;
typedef __attribute__((ext_vector_type(8))) __bf16 bf16x8;
typedef __attribute__((ext_vector_type(4))) __bf16 bf16x4;
typedef __attribute__((ext_vector_type(4))) short s16x4;
typedef __attribute__((ext_vector_type(4))) float f32x4;

#define MFMA16 __builtin_amdgcn_mfma_f32_16x16x32_bf16
#define MFMA16K16 __builtin_amdgcn_mfma_f32_16x16x16bf16_1k

__device__ __forceinline__ bf16_t f2bf(float x) {
  unsigned u = __float_as_uint(x);
  unsigned r = (u + 0x7fffu + ((u >> 16) & 1u)) >> 16;
  unsigned short s = (unsigned short)r;
  return __builtin_bit_cast(bf16_t, s);
}

// pack two f32 -> u32 of two bf16 (round-half-up): lo16 = bf16(a), hi16 = bf16(b)
__device__ __forceinline__ unsigned pkbf(float a, float b) {
  unsigned ua = __float_as_uint(a) + 0x8000u;
  unsigned ub = __float_as_uint(b) + 0x8000u;
  return __builtin_amdgcn_perm(ub, ua, 0x07060302u);
}

// async global->LDS, 16B per lane. LDS dest must be wave-uniform base + lane*16.
__device__ __forceinline__ void gld_lds16(const bf16_t* g, bf16_t* l) {
  __builtin_amdgcn_global_load_lds(
      (const __attribute__((address_space(1))) unsigned int*)g,
      (__attribute__((address_space(3))) unsigned int*)l, 16, 0, 0);
}

// ---------------- convert: x -> Xb, {Wq,Wk,Wv} -> Wqkv concat, Wo -> Wob ----
__global__ __launch_bounds__(256) void cvt_kernel(const float4* __restrict__ x,
                                                  const float4* __restrict__ wq,
                                                  const float4* __restrict__ wk,
                                                  const float4* __restrict__ wv,
                                                  const float4* __restrict__ wo,
                                                  bf16x4* __restrict__ xb,
                                                  bf16x4* __restrict__ wqkv,
                                                  bf16x4* __restrict__ wob) {
  const int NX = (2 * 2048 * 1024) / 4;  // 2,097,152
  const int NW = (1024 * 1024) / 4;      // 262,144 = 2^18
  const int TOT = NX + 4 * NW;
  for (int i = blockIdx.x * 256 + threadIdx.x; i < TOT; i += gridDim.x * 256) {
    const float4* s;
    bf16x4* d;
    if (i < NX) {
      s = x + i; d = xb + i;
    } else {
      int t = i - NX;
      int w = t >> 18;
      int o = t & (NW - 1);
      if (w == 0)      { s = wq + o; d = wqkv + o; }
      else if (w == 1) { s = wk + o; d = wqkv + NW + o; }
      else if (w == 2) { s = wv + o; d = wqkv + 2 * NW + o; }
      else             { s = wo + o; d = wob + o; }
    }
    float4 v = *s;
    bf16x4 h;
    h[0] = f2bf(v.x); h[1] = f2bf(v.y); h[2] = f2bf(v.z); h[3] = f2bf(v.w);
    *d = h;
  }
}

// ---------------- QKV GEMM: C[M,N] = A[M,K] * B[N,K]^T -----------------------
// Q,K blocks: LDS repack -> vectorized 16B stores to [b,h,s,hd] (Q pre-scaled).
// V blocks: LDS-transpose epilogue -> Vt[bh][d][s]. 128x128x64, grid (24,32).
__global__ __launch_bounds__(256) void gemm128(const bf16_t* __restrict__ A,
                                               const bf16_t* __restrict__ B,
                                               bf16_t* __restrict__ Qo,
                                               bf16_t* __restrict__ Ko,
                                               bf16_t* __restrict__ Vt,
                                               int M, int N, int K) {
  constexpr int TS = 137;  // V-transpose stride (odd: conflict-free col reads)
  constexpr int LR = 136;  // Q/K repack stride (mult of 8: 16B-aligned b128 rows)
  __shared__ __align__(16) bf16_t Sm[128 * TS];  // 35072B; aliases As/Bs staging
  bf16_t* As = Sm;
  bf16_t* Bs = Sm + 128 * 64;
  const int m0 = blockIdx.y * 128, n0 = blockIdx.x * 128;
  const int tid = threadIdx.x, lane = tid & 63;
  const int l15 = lane & 15, quad = lane >> 4;
  const int w = tid >> 6;
  const int wr = (w >> 1) * 64, wc = (w & 1) * 64;

  f32x4 acc[4][4];
#pragma unroll
  for (int i = 0; i < 4; i++)
#pragma unroll
    for (int j = 0; j < 4; j++) acc[i][j] = f32x4{0.f, 0.f, 0.f, 0.f};

  for (int k0 = 0; k0 < K; k0 += 64) {
    __syncthreads();
#pragma unroll
    for (int r = 0; r < 4; r++) {
      int c = r * 256 + tid;
      gld_lds16(A + (long)(m0 + (c >> 3)) * K + k0 + (c & 7) * 8, As + c * 8);
    }
#pragma unroll
    for (int r = 0; r < 4; r++) {
      int c = r * 256 + tid;
      gld_lds16(B + (long)(n0 + (c >> 3)) * K + k0 + (c & 7) * 8, Bs + c * 8);
    }
    __syncthreads();
#pragma unroll
    for (int ks = 0; ks < 2; ks++) {
      bf16x8 af[4], bv[4];
#pragma unroll
      for (int i = 0; i < 4; i++)
        af[i] = *(const bf16x8*)(As + (wr + i * 16 + l15) * 64 + ks * 32 + quad * 8);
#pragma unroll
      for (int j = 0; j < 4; j++)
        bv[j] = *(const bf16x8*)(Bs + (wc + j * 16 + l15) * 64 + ks * 32 + quad * 8);
#pragma unroll
      for (int i = 0; i < 4; i++)
#pragma unroll
        for (int j = 0; j < 4; j++) acc[i][j] = MFMA16(af[i], bv[j], acc[i][j], 0, 0, 0);
    }
  }

  const int mat = n0 >> 10;  // block entirely within one of Q/K/V (128 | 1024)
  const int hbase = (n0 & 1023) >> 6;  // first head in this 128-col span
  const int b = m0 >> 11;              // tile never crosses batch boundary
  const int sg0 = m0 & 2047;
  __syncthreads();  // all MFMA LDS reads done before Sm reuse

  if (mat < 2) {
    // scale2 = (1/sqrt(64))*log2(e), folded into Q before its single rounding
    const float sc = (mat == 0) ? 0.18033688011112042f : 1.0f;
    bf16_t* dst = (mat == 0) ? Qo : Ko;
#pragma unroll
    for (int i = 0; i < 4; i++)
#pragma unroll
      for (int j = 0; j < 4; j++) {
        int col = wc + j * 16 + l15;
#pragma unroll
        for (int r = 0; r < 4; r++) {
          int row = wr + i * 16 + quad * 4 + r;
          Sm[row * LR + col] = f2bf(acc[i][j][r] * sc);
        }
      }
    __syncthreads();
#pragma unroll
    for (int u = 0; u < 8; u++) {
      int id = u * 256 + tid;
      int row = id >> 4, ck = id & 15;  // 16 thr per row: b128 row reads, 2-way
      int head = hbase + (ck >> 3), hd0 = (ck & 7) * 8;
      bf16x8 v = *(const bf16x8*)(Sm + row * LR + ck * 8);
      *(bf16x8*)(dst + (((long)(b * 16 + head) * 2048 + (sg0 + row)) << 6) + hd0) = v;
    }
  } else {
    // V block: transpose 128(s) x 128(c) tile through LDS, write Vt[bh][d][s]
#pragma unroll
    for (int i = 0; i < 4; i++)
#pragma unroll
      for (int j = 0; j < 4; j++) {
        int col = wc + j * 16 + l15;
#pragma unroll
        for (int r = 0; r < 4; r++) {
          int row = wr + i * 16 + quad * 4 + r;
          Sm[row * TS + col] = f2bf(acc[i][j][r]);
        }
      }
    __syncthreads();
#pragma unroll
    for (int u = 0; u < 8; u++) {
      int id = u * 256 + tid;
      int col = id >> 4, sc = id & 15;  // consecutive tid -> consecutive s-chunk
      int head = hbase + (col >> 6), hd = col & 63;
      bf16x8 v;
#pragma unroll
      for (int vv = 0; vv < 8; vv++) v[vv] = Sm[(sc * 8 + vv) * TS + col];
      *(bf16x8*)(Vt + ((long)(b * 16 + head) * 64 + hd) * 2048 + sg0 + sc * 8) = v;
    }
  }
}

// ---------------- attention unit: one 64q x (JTN*16)kv step -----------------
// Branch-free; Q pre-scaled so no per-element scale. Mask only jt >= JM0
// (compile-time). S^T = K.Q^T; P^T packed in-register as B-frags of
// mfma_16x16x16bf16; O^T += V^T.P^T from LDS Vl.
template <int JTN, int JM0, int PS>
__device__ __forceinline__ void attn_unit(const bf16_t* __restrict__ Kb, int kv0,
                                          const bf16_t* Vlb, const bf16x8* qf,
                                          int q_abs, float& m_i, float& l_i,
                                          f32x4* Oacc, int l15, int quad) {
  f32x4 S[JTN];
#pragma unroll
  for (int jt = 0; jt < JTN; jt++) {
    const bf16_t* kr = Kb + (long)(kv0 + jt * 16 + l15) * 64 + quad * 8;
    bf16x8 ka = *(const bf16x8*)kr;
    bf16x8 kb = *(const bf16x8*)(kr + 32);
    f32x4 s = f32x4{0.f, 0.f, 0.f, 0.f};
    s = MFMA16(ka, qf[0], s, 0, 0, 0);
    s = MFMA16(kb, qf[1], s, 0, 0, 0);
    S[jt] = s;
  }
#pragma unroll
  for (int jt = JM0; jt < JTN; jt++) {
    int kvb = kv0 + jt * 16 + quad * 4;
#pragma unroll
    for (int r = 0; r < 4; r++)
      if (kvb + r > q_abs) S[jt][r] = -1e30f;
  }
  float mx = -1e30f;
#pragma unroll
  for (int jt = 0; jt < JTN; jt++)
#pragma unroll
    for (int r = 0; r < 4; r++) mx = fmaxf(mx, S[jt][r]);
  mx = fmaxf(mx, __shfl_xor(mx, 16, 64));
  mx = fmaxf(mx, __shfl_xor(mx, 32, 64));
  float mnew = fmaxf(m_i, mx);
  float alpha = exp2f(m_i - mnew);
  float rs = 0.f;
#pragma unroll
  for (int jt = 0; jt < JTN; jt++)
#pragma unroll
    for (int r = 0; r < 4; r++) {
      float pv = exp2f(S[jt][r] - mnew);
      S[jt][r] = pv;
      rs += pv;
    }
  rs += __shfl_xor(rs, 16, 64);
  rs += __shfl_xor(rs, 32, 64);
  l_i = l_i * alpha + rs;
  m_i = mnew;
#pragma unroll
  for (int n = 0; n < 4; n++) Oacc[n] *= alpha;
#pragma unroll
  for (int jt = 0; jt < JTN; jt++) {
    int2 pk;
    pk.x = (int)pkbf(S[jt][0], S[jt][1]);
    pk.y = (int)pkbf(S[jt][2], S[jt][3]);
    s16x4 pb = __builtin_bit_cast(s16x4, pk);
#pragma unroll
    for (int n = 0; n < 4; n++) {
      s16x4 av = *(const s16x4*)(Vlb + (n * 16 + l15) * PS + jt * 16 + quad * 4);
      Oacc[n] = MFMA16K16(av, pb, Oacc[n], 0, 0, 0);
    }
  }
}

// ---------------- flash attention, XCD-localized ----------------------------
// Q(pre-scaled),K: [32][2048][64]; Vt: [32][64][2048]; O: [4096][1024].
// grid (8, 128); block 256 (4 waves, wave w owns q rows w*16..w*16+15).
//   x = blockIdx.x in [0,8)  -> XCD id (linear%8 = x since gridDim.x=8)
//   g = y>>5, yr = y&31; bh = g*8 + x  -> each head entirely on one XCD:
//   per-XCD working set 4 heads x (Q+K+V) = 3MB < 4MB L2.
//   qt = (g&1) ? 31-yr : yr -> same-CU co-resident blocks (delta linear 256 =>
//   delta g 1, same x/yr) get {yr,31-yr,yr,31-yr} = exactly 34 units per CU.
// V LDS double-buffer + register prefetch: ONE barrier per kv-tile.
__global__ __launch_bounds__(256, 4) void attn7(const bf16_t* __restrict__ Q,
                                                const bf16_t* __restrict__ Kp,
                                                const bf16_t* __restrict__ Vt,
                                                bf16_t* __restrict__ O) {
  constexpr int PS = 136;
  __shared__ __align__(16) bf16_t Vl[2][64 * PS];  // 2 x 17.4KB
  const int g = blockIdx.y >> 5, yr = blockIdx.y & 31;
  const int bh = g * 8 + blockIdx.x;
  const int qt = (g & 1) ? (31 - yr) : yr;
  const int q0 = qt * 64;
  const int nkt = (qt >> 1) + 1;
  const int tid = threadIdx.x, lane = tid & 63;
  const int l15 = lane & 15, quad = lane >> 4;
  const int w = tid >> 6;
  const bf16_t* Qb = Q + (long)bh * 2048 * 64;
  const bf16_t* Kb = Kp + (long)bh * 2048 * 64;
  const bf16_t* Vg = Vt + (long)bh * 64 * 2048;
  const int bb = bh >> 4, hh = bh & 15;

  bf16x8 qf[2];
#pragma unroll
  for (int ks = 0; ks < 2; ks++)
    qf[ks] = *(const bf16x8*)(Qb + (long)(q0 + w * 16 + l15) * 64 + ks * 32 + quad * 8);

  f32x4 Oacc[4];
#pragma unroll
  for (int n = 0; n < 4; n++) Oacc[n] = f32x4{0.f, 0.f, 0.f, 0.f};
  float m_i = -1e30f, l_i = 0.f;
  const int q_abs = q0 + w * 16 + l15;

  // stage V tile 0 -> Vl[0]  (64x128 = 256 thr x 4 x 16B)
  bf16x8 vr[4];
#pragma unroll
  for (int r = 0; r < 4; r++) {
    int c = r * 256 + tid;
    vr[r] = *(const bf16x8*)(Vg + (long)(c >> 4) * 2048 + (c & 15) * 8);
  }
#pragma unroll
  for (int r = 0; r < 4; r++) {
    int c = r * 256 + tid;
    *(bf16x8*)(&Vl[0][(c >> 4) * PS + (c & 15) * 8]) = vr[r];
  }

  for (int kt = 0; kt < nkt - 1; kt++) {  // full (unmasked) tiles
    const bf16_t* Vcur = &Vl[kt & 1][0];
    bf16_t* Vnxt = &Vl[(kt + 1) & 1][0];
    __syncthreads();  // Vl[kt&1] staged; all waves past previous tile's reads
    const int kvn = (kt + 1) * 128;
#pragma unroll
    for (int r = 0; r < 4; r++) {  // prefetch next V tile
      int c = r * 256 + tid;
      vr[r] = *(const bf16x8*)(Vg + (long)(c >> 4) * 2048 + kvn + (c & 15) * 8);
    }
    attn_unit<8, 8, PS>(Kb, kt * 128, Vcur, qf, q_abs, m_i, l_i, Oacc, l15, quad);
#pragma unroll
    for (int r = 0; r < 4; r++) {
      int c = r * 256 + tid;
      *(bf16x8*)(&Vnxt[(c >> 4) * PS + (c & 15) * 8]) = vr[r];
    }
  }

  __syncthreads();
  const bf16_t* Vlast = &Vl[(nkt - 1) & 1][0];
  const int kvl = (nkt - 1) * 128;
  if (qt & 1)
    attn_unit<8, 4, PS>(Kb, kvl, Vlast, qf, q_abs, m_i, l_i, Oacc, l15, quad);
  else
    attn_unit<4, 0, PS>(Kb, kvl, Vlast, qf, q_abs, m_i, l_i, Oacc, l15, quad);

  // epilogue: lane holds O^T[d=n*16+quad*4+r][q=l15] -> O[row q][col hh*64+d]
  const float inv = 1.0f / l_i;
  bf16_t* orow = O + ((long)bb * 2048 + q_abs) * 1024 + hh * 64;
#pragma unroll
  for (int n = 0; n < 4; n++) {
    int2 pk;
    pk.x = (int)pkbf(Oacc[n][0] * inv, Oacc[n][1] * inv);
    pk.y = (int)pkbf(Oacc[n][2] * inv, Oacc[n][3] * inv);
    *(int2*)(orow + n * 16 + quad * 4) = pk;
  }
}

// ---------------- final GEMM: C[M,N] f32 = A[M,K] bf16 * B[N,K]^T bf16 ------
// 128x64x64 tile, 4 waves row-split (32 rows each). grid (N/64, M/128) = 512.
__global__ __launch_bounds__(256) void gemm64(const bf16_t* __restrict__ A,
                                              const bf16_t* __restrict__ B,
                                              float* __restrict__ C,
                                              int M, int N, int K) {
  __shared__ __align__(16) bf16_t As[128 * 64];
  __shared__ __align__(16) bf16_t Bs[64 * 64];
  const int m0 = blockIdx.y * 128, n0 = blockIdx.x * 64;
  const int tid = threadIdx.x, lane = tid & 63;
  const int l15 = lane & 15, quad = lane >> 4;
  const int w = tid >> 6;

  f32x4 acc[2][4];
#pragma unroll
  for (int i = 0; i < 2; i++)
#pragma unroll
    for (int j = 0; j < 4; j++) acc[i][j] = f32x4{0.f, 0.f, 0.f, 0.f};

  for (int k0 = 0; k0 < K; k0 += 64) {
    __syncthreads();
#pragma unroll
    for (int r = 0; r < 4; r++) {
      int c = r * 256 + tid;
      gld_lds16(A + (long)(m0 + (c >> 3)) * K + k0 + (c & 7) * 8, As + c * 8);
    }
#pragma unroll
    for (int r = 0; r < 2; r++) {
      int c = r * 256 + tid;
      gld_lds16(B + (long)(n0 + (c >> 3)) * K + k0 + (c & 7) * 8, Bs + c * 8);
    }
    __syncthreads();
#pragma unroll
    for (int ks = 0; ks < 2; ks++) {
      bf16x8 af[2], bv[4];
#pragma unroll
      for (int i = 0; i < 2; i++)
        af[i] = *(const bf16x8*)(As + (w * 32 + i * 16 + l15) * 64 + ks * 32 + quad * 8);
#pragma unroll
      for (int j = 0; j < 4; j++)
        bv[j] = *(const bf16x8*)(Bs + (j * 16 + l15) * 64 + ks * 32 + quad * 8);
#pragma unroll
      for (int i = 0; i < 2; i++)
#pragma unroll
        for (int j = 0; j < 4; j++) acc[i][j] = MFMA16(af[i], bv[j], acc[i][j], 0, 0, 0);
    }
  }

#pragma unroll
  for (int i = 0; i < 2; i++)
#pragma unroll
    for (int j = 0; j < 4; j++) {
      int col = n0 + j * 16 + l15;
#pragma unroll
      for (int r = 0; r < 4; r++) {
        int row = m0 + w * 32 + i * 16 + quad * 4 + r;
        C[(long)row * N + col] = acc[i][j][r];
      }
    }
}

// ============================================================================
extern "C" void kernel_launch(void* const* d_in, const int* in_sizes, int n_in,
                              void* d_out, int out_size, void* d_ws, size_t ws_size,
                              hipStream_t stream) {
  const float* x = (const float*)d_in[0];
  const float* Wq = (const float*)d_in[1];
  const float* Wk = (const float*)d_in[2];
  const float* Wv = (const float*)d_in[3];
  const float* Wo = (const float*)d_in[4];
  float* out = (float*)d_out;

  const long M4 = 4L * 1024 * 1024;  // 4M bf16 elems = 8MB
  dim3 blk(256);

  bf16_t* Qb = (bf16_t*)d_ws;      // [32][2048][64] (pre-scaled)
  bf16_t* Kb = Qb + M4;            // [32][2048][64]
  bf16_t* Ob = Kb + M4;            // [4096][1024] (attn output)
  bf16_t* Vtg = Ob + M4;           // [32][64][2048] (V transposed, from gemm128)
  bf16_t* Xb = Vtg + M4;           // [4096][1024]
  bf16_t* Wqkv = Xb + M4;          // [3072][1024]
  bf16_t* Wob = Wqkv + 3L * 1024 * 1024;  // [1024][1024]

  cvt_kernel<<<4096, blk, 0, stream>>>((const float4*)x, (const float4*)Wq,
                                       (const float4*)Wk, (const float4*)Wv,
                                       (const float4*)Wo, (bf16x4*)Xb,
                                       (bf16x4*)Wqkv, (bf16x4*)Wob);
  gemm128<<<dim3(24, 32), blk, 0, stream>>>(Xb, Wqkv, Qb, Kb, Vtg, 4096, 3072, 1024);
  attn7<<<dim3(8, 128), blk, 0, stream>>>(Qb, Kb, Vtg, Ob);
  gemm64<<<dim3(16, 32), blk, 0, stream>>>(Ob, Wob, out, 4096, 1024, 1024);
}